// Round 1
// baseline (8986.753 us; speedup 1.0000x reference)
//
#include <hip/hip_runtime.h>
#include <math.h>

// Problem: B=64, T=512, I=128, H=1024, O=128; gates order i,j,f,o; relu activations.
#define Bsz 64
#define Tn  512
#define In  128
#define Hn  1024
#define KT  1152      // I + H
#define NBLK 128      // persistent blocks; each owns 8 hidden cols (x4 gates = 32 cols)

typedef __attribute__((ext_vector_type(8))) short bf16x8;   // 8 bf16 = 4 VGPRs (MFMA A/B frag)
typedef __attribute__((ext_vector_type(4))) short s16x4;
typedef __attribute__((ext_vector_type(4))) float f32x4;

__device__ __forceinline__ unsigned short f2bf(float f) {
  union { float f; unsigned u; } x; x.f = f;
  unsigned r = x.u + 0x7FFFu + ((x.u >> 16) & 1u);   // RNE
  return (unsigned short)(r >> 16);
}
__device__ __forceinline__ float sigmoidf_(float x) { return 1.0f / (1.0f + __expf(-x)); }

// ---------------- prep: X (fp32) -> Xb (bf16), elementwise ----------------
__global__ __launch_bounds__(256) void cast_x_kernel(const float* __restrict__ in,
                                                     unsigned short* __restrict__ out) {
  int i = blockIdx.x * 256 + threadIdx.x;          // f32x4 index; total 4194304/4 = 1048576
  f32x4 v = ((const f32x4*)in)[i];
  s16x4 o;
  o.x = (short)f2bf(v.x); o.y = (short)f2bf(v.y);
  o.z = (short)f2bf(v.z); o.w = (short)f2bf(v.w);
  ((s16x4*)out)[i] = o;
}

// -------- prep: transpose+cast fp32 [R][C] -> bf16 [C][ldo] (64x64 LDS tiles) --------
__global__ __launch_bounds__(256) void transpose_cast_kernel(const float* __restrict__ in,
                                                             unsigned short* __restrict__ out,
                                                             int R, int C, int ldo, int tilesR) {
  __shared__ unsigned short tile[64][73];          // 73 pad -> <=2-way banks on transposed read
  int br = blockIdx.x % tilesR, bc = blockIdx.x / tilesR;
  int r0 = br << 6, c0 = bc << 6;
  for (int e = threadIdx.x; e < 4096; e += 256) {
    int r = e >> 6, c = e & 63;
    tile[r][c] = f2bf(in[(size_t)(r0 + r) * C + (c0 + c)]);
  }
  __syncthreads();
  for (int e = threadIdx.x; e < 4096; e += 256) {
    int c = e >> 6, r = e & 63;                    // consecutive tid -> consecutive r: coalesced store
    out[(size_t)(c0 + c) * ldo + (r0 + r)] = tile[r][c];
  }
}

// ---------------- persistent LSTM recurrence ----------------
// Block blk owns hidden cols j in [blk*8, blk*8+8), gate cols {j, H+j, 2H+j, 3H+j}.
// 8 waves = (2 batch-halves mh) x (4 K-quarters kq); B-frags register-resident (72 VGPR).
__global__ __launch_bounds__(512, 2) void lstm_kernel(
    const unsigned short* __restrict__ Xb,    // [64][512][128] bf16
    const unsigned short* __restrict__ WkT,   // [4096][1152]  bf16 (col-major-in-k)
    const float* __restrict__ bias,           // [4096]
    unsigned short* __restrict__ hs,          // [512][64][1024] bf16 (output history)
    unsigned* __restrict__ arrive, unsigned* __restrict__ release)
{
  __shared__ float Z[64 * 36];                // z tile [64 batch][32 cols], ld=36 (bank pad)
  const int tid = threadIdx.x;
  const int blk = blockIdx.x;
  const int w   = tid >> 6;
  const int mh  = w & 1;                      // batch half (32 rows)
  const int kq  = w >> 1;                     // K quarter (288 of 1152)
  const int l   = tid & 63, q = l >> 4, n16 = l & 15;

  // ---- load register-resident B fragments (once) ----
  bf16x8 Bf[2][9];
#pragma unroll
  for (int nt = 0; nt < 2; ++nt) {
    int cl   = nt * 16 + n16;                                  // local col 0..31
    int gcol = (cl >> 3) * Hn + blk * 8 + (cl & 7);            // gate*1024 + j
    const unsigned short* bp = WkT + (size_t)gcol * KT + kq * 288 + q * 8;
#pragma unroll
    for (int ks = 0; ks < 9; ++ks)
      Bf[nt][ks] = *(const bf16x8*)(bp + ks * 32);
  }

  // ---- epilogue constants: thread = (batch eb, col ej) ----
  const int eb = tid >> 3, ej = tid & 7;
  const float bi  = bias[           blk * 8 + ej];
  const float bg  = bias[    Hn   + blk * 8 + ej];
  const float bfg = bias[2 * Hn   + blk * 8 + ej] + 1.0f;      // TF forget bias
  const float bo  = bias[3 * Hn   + blk * 8 + ej];
  float cst = 0.0f;                                            // cell state, persistent in VGPR

  const int b0 = mh * 32 + n16;                                // A rows (two 16-batch tiles)
  const int b1 = b0 + 16;

  for (int t = 0; t < Tn; ++t) {
    f32x4 a00 = {0,0,0,0}, a01 = {0,0,0,0}, a10 = {0,0,0,0}, a11 = {0,0,0,0};
    const unsigned short* hrow = hs + (size_t)(t - 1) * (Bsz * Hn);

    if (t > 0) {
#pragma unroll
      for (int ks = 0; ks < 9; ++ks) {
        int kbase = kq * 288 + ks * 32;                        // lane adds q*8
        bf16x8 A0, A1;
        if (kq == 0 && ks < 4) {                               // x-part (k < 128), wave-uniform
          const unsigned short* x0 = Xb + ((size_t)b0 * Tn + t) * In + kbase + q * 8;
          const unsigned short* x1 = Xb + ((size_t)b1 * Tn + t) * In + kbase + q * 8;
          A0 = *(const bf16x8*)x0;  A1 = *(const bf16x8*)x1;
        } else {                                               // h-part from hs[t-1]
          int kh = kbase - 128 + q * 8;
          A0 = *(const bf16x8*)(hrow + (size_t)b0 * Hn + kh);
          A1 = *(const bf16x8*)(hrow + (size_t)b1 * Hn + kh);
        }
        a00 = __builtin_amdgcn_mfma_f32_16x16x32_bf16(A0, Bf[0][ks], a00, 0, 0, 0);
        a01 = __builtin_amdgcn_mfma_f32_16x16x32_bf16(A0, Bf[1][ks], a01, 0, 0, 0);
        a10 = __builtin_amdgcn_mfma_f32_16x16x32_bf16(A1, Bf[0][ks], a10, 0, 0, 0);
        a11 = __builtin_amdgcn_mfma_f32_16x16x32_bf16(A1, Bf[1][ks], a11, 0, 0, 0);
      }
    } else if (kq == 0) {                                      // t==0: h==0, x-part only
#pragma unroll
      for (int ks = 0; ks < 4; ++ks) {
        const unsigned short* x0 = Xb + ((size_t)b0 * Tn) * In + ks * 32 + q * 8;
        const unsigned short* x1 = Xb + ((size_t)b1 * Tn) * In + ks * 32 + q * 8;
        bf16x8 A0 = *(const bf16x8*)x0, A1 = *(const bf16x8*)x1;
        a00 = __builtin_amdgcn_mfma_f32_16x16x32_bf16(A0, Bf[0][ks], a00, 0, 0, 0);
        a01 = __builtin_amdgcn_mfma_f32_16x16x32_bf16(A0, Bf[1][ks], a01, 0, 0, 0);
        a10 = __builtin_amdgcn_mfma_f32_16x16x32_bf16(A1, Bf[0][ks], a10, 0, 0, 0);
        a11 = __builtin_amdgcn_mfma_f32_16x16x32_bf16(A1, Bf[1][ks], a11, 0, 0, 0);
      }
    }

    // ---- K-split reduction into LDS (kq0 writes, kq1..3 atomic-add) ----
    if (kq == 0) {
#pragma unroll
      for (int r = 0; r < 4; ++r) {
        int row0 = mh * 32 + q * 4 + r;
        Z[ row0       * 36      + n16] = a00[r];
        Z[ row0       * 36 + 16 + n16] = a01[r];
        Z[(row0 + 16) * 36      + n16] = a10[r];
        Z[(row0 + 16) * 36 + 16 + n16] = a11[r];
      }
    }
    __syncthreads();
    if (kq != 0) {
#pragma unroll
      for (int r = 0; r < 4; ++r) {
        int row0 = mh * 32 + q * 4 + r;
        atomicAdd(&Z[ row0       * 36      + n16], a00[r]);
        atomicAdd(&Z[ row0       * 36 + 16 + n16], a01[r]);
        atomicAdd(&Z[(row0 + 16) * 36      + n16], a10[r]);
        atomicAdd(&Z[(row0 + 16) * 36 + 16 + n16], a11[r]);
      }
    }
    __syncthreads();

    // ---- gates + cell update: one (batch, col) per thread ----
    float zi = Z[eb * 36      + ej] + bi;
    float zg = Z[eb * 36 +  8 + ej] + bg;
    float zf = Z[eb * 36 + 16 + ej] + bfg;
    float zo = Z[eb * 36 + 24 + ej] + bo;
    float ig = sigmoidf_(zi);
    float g  = fmaxf(zg, 0.0f);
    float ff = sigmoidf_(zf);
    float oo = sigmoidf_(zo);
    cst = ff * cst + ig * g;
    float hn = oo * fmaxf(cst, 0.0f);
    hs[(size_t)t * (Bsz * Hn) + (size_t)eb * Hn + blk * 8 + ej] = f2bf(hn);

    // ---- grid barrier (monotone counters; relaxed spin, one acquire at exit) ----
    if (t < Tn - 1) {
      __syncthreads();
      if (tid == 0) {
        unsigned target = (unsigned)t + 1u;
        unsigned old = __hip_atomic_fetch_add(arrive, 1u, __ATOMIC_ACQ_REL, __HIP_MEMORY_SCOPE_AGENT);
        if (old == target * NBLK - 1u) {
          __hip_atomic_store(release, target, __ATOMIC_RELEASE, __HIP_MEMORY_SCOPE_AGENT);
        } else {
          while (__hip_atomic_load(release, __ATOMIC_RELAXED, __HIP_MEMORY_SCOPE_AGENT) < target) {
            __builtin_amdgcn_s_sleep(8);
          }
          (void)__hip_atomic_load(release, __ATOMIC_ACQUIRE, __HIP_MEMORY_SCOPE_AGENT);
        }
      }
      __syncthreads();
    }
  }
}

// ---------------- dense epilogue: out[b,t,:] = hs_row @ Wd + bd ----------------
__global__ __launch_bounds__(256) void dense_kernel(
    const unsigned short* __restrict__ hs,    // [32768][1024] bf16, row = t*64+b
    const unsigned short* __restrict__ WdT,   // [128][1024] bf16
    const float* __restrict__ bd,             // [128]
    float* __restrict__ out)                  // [64][512][128] fp32
{
  const int tid = threadIdx.x;
  const int w = tid >> 6, l = tid & 63, q = l >> 4, n16 = l & 15;
  const int R0 = blockIdx.x * 64 + w * 16;
  f32x4 acc[8];
#pragma unroll
  for (int i = 0; i < 8; ++i) acc[i] = (f32x4){0, 0, 0, 0};
  const unsigned short* arow = hs + (size_t)(R0 + n16) * Hn + q * 8;
#pragma unroll 4
  for (int ks = 0; ks < 32; ++ks) {
    bf16x8 A = *(const bf16x8*)(arow + ks * 32);
#pragma unroll
    for (int nt = 0; nt < 8; ++nt) {
      bf16x8 Bf = *(const bf16x8*)(WdT + (size_t)(nt * 16 + n16) * Hn + ks * 32 + q * 8);
      acc[nt] = __builtin_amdgcn_mfma_f32_16x16x32_bf16(A, Bf, acc[nt], 0, 0, 0);
    }
  }
#pragma unroll
  for (int nt = 0; nt < 8; ++nt) {
    int col = nt * 16 + n16;
    float bdv = bd[col];
#pragma unroll
    for (int r = 0; r < 4; ++r) {
      int R = R0 + q * 4 + r;
      int b = R & 63, t = R >> 6;
      out[((size_t)b * Tn + t) * 128 + col] = acc[nt][r] + bdv;
    }
  }
}

// ---------------- launcher ----------------
extern "C" void kernel_launch(void* const* d_in, const int* in_sizes, int n_in,
                              void* d_out, int out_size, void* d_ws, size_t ws_size,
                              hipStream_t stream) {
  const float* X    = (const float*)d_in[0];   // [64][512][128]
  const float* Wk   = (const float*)d_in[1];   // [1152][4096]
  const float* bias = (const float*)d_in[2];   // [4096]
  const float* Wd   = (const float*)d_in[3];   // [1024][128]
  const float* bd   = (const float*)d_in[4];   // [128]
  float* out = (float*)d_out;

  // ws layout (bytes):                        size        end
  char* ws = (char*)d_ws;
  unsigned short* Xb  = (unsigned short*)(ws);              //  8,388,608
  unsigned short* WkT = (unsigned short*)(ws + 8388608);    //  9,437,184
  unsigned short* WdT = (unsigned short*)(ws + 17825792);   //    262,144
  unsigned short* hs  = (unsigned short*)(ws + 18087936);   // 67,108,864
  unsigned*       syn = (unsigned*)      (ws + 85196800);   //        256  (arrive @0, release @64)

  hipMemsetAsync(syn, 0, 256, stream);
  cast_x_kernel<<<4096, 256, 0, stream>>>(X, Xb);
  transpose_cast_kernel<<<1152, 256, 0, stream>>>(Wk, WkT, 1152, 4096, 1152, 18);
  transpose_cast_kernel<<<32, 256, 0, stream>>>(Wd, WdT, 1024, 128, 1024, 16);
  lstm_kernel<<<NBLK, 512, 0, stream>>>(Xb, WkT, bias, hs, syn, syn + 64);
  dense_kernel<<<512, 256, 0, stream>>>(hs, WdT, bd, out);
}

// Round 2
// 7546.462 us; speedup vs baseline: 1.1909x; 1.1909x over previous
//
#include <hip/hip_runtime.h>
#include <math.h>

// Problem: B=64, T=512, I=128, H=1024, O=128; gates order i,j,f,o; relu activations.
#define Bsz 64
#define Tn  512
#define In  128
#define Hn  1024
#define KT  1152      // I + H
#define NBLK 128      // persistent blocks; each owns 8 hidden cols (x4 gates = 32 cols)

typedef __attribute__((ext_vector_type(8))) short bf16x8;   // 8 bf16 = 4 VGPRs (MFMA A/B frag)
typedef __attribute__((ext_vector_type(4))) short s16x4;
typedef __attribute__((ext_vector_type(4))) float f32x4;
typedef __attribute__((ext_vector_type(4))) int   i32x4;

// Raw buffer intrinsics (legacy v4i32-rsrc form, as used by CK).
// cpol 17 = SC0|SC1 on gfx950 -> performed at the IF coherence point (cross-XCD coherent),
// letting us drop ALL agent-scope acquire/release fences (no buffer_wbl2/buffer_inv walks).
__device__ i32x4 llvm_amdgcn_raw_buffer_load_i32x4(i32x4 srsrc, int voffset, int soffset, int cpol) __asm("llvm.amdgcn.raw.buffer.load.v4i32");
__device__ void  llvm_amdgcn_raw_buffer_store_i16(short vdata, i32x4 srsrc, int voffset, int soffset, int cpol) __asm("llvm.amdgcn.raw.buffer.store.i16");

union B128 { i32x4 i; bf16x8 h; };

__device__ __forceinline__ i32x4 make_srd(const void* p, int bytes) {
  i32x4 r;
  r.x = (int)(unsigned)(unsigned long long)p;
  r.y = (int)((unsigned long long)p >> 32);   // stride = 0
  r.z = bytes;                                // num_records (bytes when stride==0)
  r.w = 0x00020000;                           // raw dword access
  return r;
}

__device__ __forceinline__ unsigned short f2bf(float f) {
  union { float f; unsigned u; } x; x.f = f;
  unsigned r = x.u + 0x7FFFu + ((x.u >> 16) & 1u);   // RNE
  return (unsigned short)(r >> 16);
}
__device__ __forceinline__ float sigmoidf_(float x) { return 1.0f / (1.0f + __expf(-x)); }

// ---------------- prep: X (fp32) -> Xb (bf16), elementwise ----------------
__global__ __launch_bounds__(256) void cast_x_kernel(const float* __restrict__ in,
                                                     unsigned short* __restrict__ out) {
  int i = blockIdx.x * 256 + threadIdx.x;
  f32x4 v = ((const f32x4*)in)[i];
  s16x4 o;
  o.x = (short)f2bf(v.x); o.y = (short)f2bf(v.y);
  o.z = (short)f2bf(v.z); o.w = (short)f2bf(v.w);
  ((s16x4*)out)[i] = o;
}

// -------- prep: transpose+cast fp32 [R][C] -> bf16 [C][ldo] (64x64 LDS tiles) --------
__global__ __launch_bounds__(256) void transpose_cast_kernel(const float* __restrict__ in,
                                                             unsigned short* __restrict__ out,
                                                             int R, int C, int ldo, int tilesR) {
  __shared__ unsigned short tile[64][73];
  int br = blockIdx.x % tilesR, bc = blockIdx.x / tilesR;
  int r0 = br << 6, c0 = bc << 6;
  for (int e = threadIdx.x; e < 4096; e += 256) {
    int r = e >> 6, c = e & 63;
    tile[r][c] = f2bf(in[(size_t)(r0 + r) * C + (c0 + c)]);
  }
  __syncthreads();
  for (int e = threadIdx.x; e < 4096; e += 256) {
    int c = e >> 6, r = e & 63;
    out[(size_t)(c0 + c) * ldo + (r0 + r)] = tile[r][c];
  }
}

// ---------------- persistent LSTM recurrence ----------------
// Block blk owns hidden cols j in [blk*8, blk*8+8), gate cols {j, H+j, 2H+j, 3H+j}.
// 8 waves = (2 batch-halves mh) x (4 K-quarters kq); B-frags register-resident.
// hs hand-off is instruction-level coherent (sc0|sc1); barrier is pure relaxed atomics.
__global__ __launch_bounds__(512, 2) void lstm_kernel(
    const unsigned short* __restrict__ Xb,    // [64][512][128] bf16
    const unsigned short* __restrict__ WkT,   // [4096][1152]  bf16 (col-major-in-k)
    const float* __restrict__ bias,           // [4096]
    unsigned short* __restrict__ hs,          // [512][64][1024] bf16 (output history)
    unsigned* __restrict__ arrive, unsigned* __restrict__ release)
{
  __shared__ float Z[64 * 36];                // z tile [64 batch][32 cols], ld=36 (bank pad)
  const int tid = threadIdx.x;
  const int blk = blockIdx.x;
  const int w   = tid >> 6;
  const int mh  = w & 1;                      // batch half (32 rows)
  const int kq  = w >> 1;                     // K quarter (288 of 1152)
  const int l   = tid & 63, q = l >> 4, n16 = l & 15;

  const i32x4 hsrd = make_srd(hs, Tn * Bsz * Hn * 2);

  // ---- load register-resident B fragments (once) ----
  bf16x8 Bf[2][9];
#pragma unroll
  for (int nt = 0; nt < 2; ++nt) {
    int cl   = nt * 16 + n16;                                  // local col 0..31
    int gcol = (cl >> 3) * Hn + blk * 8 + (cl & 7);            // gate*1024 + j
    const unsigned short* bp = WkT + (size_t)gcol * KT + kq * 288 + q * 8;
#pragma unroll
    for (int ks = 0; ks < 9; ++ks)
      Bf[nt][ks] = *(const bf16x8*)(bp + ks * 32);
  }

  // ---- epilogue constants: thread = (batch eb, col ej) ----
  const int eb = tid >> 3, ej = tid & 7;
  const float bi  = bias[           blk * 8 + ej];
  const float bg  = bias[    Hn   + blk * 8 + ej];
  const float bfg = bias[2 * Hn   + blk * 8 + ej] + 1.0f;      // TF forget bias
  const float bo  = bias[3 * Hn   + blk * 8 + ej];
  const int   hst_off = (eb * Hn + blk * 8 + ej) * 2;          // per-thread h store (byte, sans t)
  float cst = 0.0f;                                            // cell state, persistent in VGPR

  const int b0 = mh * 32 + n16;                                // A rows (two 16-batch tiles)
  const int b1 = b0 + 16;

  for (int t = 0; t < Tn; ++t) {
    f32x4 a00 = {0,0,0,0}, a01 = {0,0,0,0}, a10 = {0,0,0,0}, a11 = {0,0,0,0};
    const int hb = (t - 1) * (Bsz * Hn * 2);                   // byte base of hs[t-1] (t>0 only)

    if (t > 0) {
#pragma unroll
      for (int ks = 0; ks < 9; ++ks) {
        int kbase = kq * 288 + ks * 32;
        bf16x8 A0, A1;
        if (kq == 0 && ks < 4) {                               // x-part (k < 128), wave-uniform
          const unsigned short* x0 = Xb + ((size_t)b0 * Tn + t) * In + kbase + q * 8;
          const unsigned short* x1 = Xb + ((size_t)b1 * Tn + t) * In + kbase + q * 8;
          A0 = *(const bf16x8*)x0;  A1 = *(const bf16x8*)x1;
        } else {                                               // h-part from hs[t-1], coherent load
          int kh2 = (kbase - 128 + q * 8) * 2;
          B128 u0, u1;
          u0.i = llvm_amdgcn_raw_buffer_load_i32x4(hsrd, hb + (b0 << 11) + kh2, 0, 17);
          u1.i = llvm_amdgcn_raw_buffer_load_i32x4(hsrd, hb + (b1 << 11) + kh2, 0, 17);
          A0 = u0.h; A1 = u1.h;
        }
        a00 = __builtin_amdgcn_mfma_f32_16x16x32_bf16(A0, Bf[0][ks], a00, 0, 0, 0);
        a01 = __builtin_amdgcn_mfma_f32_16x16x32_bf16(A0, Bf[1][ks], a01, 0, 0, 0);
        a10 = __builtin_amdgcn_mfma_f32_16x16x32_bf16(A1, Bf[0][ks], a10, 0, 0, 0);
        a11 = __builtin_amdgcn_mfma_f32_16x16x32_bf16(A1, Bf[1][ks], a11, 0, 0, 0);
      }
    } else if (kq == 0) {                                      // t==0: h==0, x-part only
#pragma unroll
      for (int ks = 0; ks < 4; ++ks) {
        const unsigned short* x0 = Xb + ((size_t)b0 * Tn) * In + ks * 32 + q * 8;
        const unsigned short* x1 = Xb + ((size_t)b1 * Tn) * In + ks * 32 + q * 8;
        bf16x8 A0 = *(const bf16x8*)x0, A1 = *(const bf16x8*)x1;
        a00 = __builtin_amdgcn_mfma_f32_16x16x32_bf16(A0, Bf[0][ks], a00, 0, 0, 0);
        a01 = __builtin_amdgcn_mfma_f32_16x16x32_bf16(A0, Bf[1][ks], a01, 0, 0, 0);
        a10 = __builtin_amdgcn_mfma_f32_16x16x32_bf16(A1, Bf[0][ks], a10, 0, 0, 0);
        a11 = __builtin_amdgcn_mfma_f32_16x16x32_bf16(A1, Bf[1][ks], a11, 0, 0, 0);
      }
    }

    // ---- K-split reduction into LDS (kq0 writes, kq1..3 atomic-add) ----
    if (kq == 0) {
#pragma unroll
      for (int r = 0; r < 4; ++r) {
        int row0 = mh * 32 + q * 4 + r;
        Z[ row0       * 36      + n16] = a00[r];
        Z[ row0       * 36 + 16 + n16] = a01[r];
        Z[(row0 + 16) * 36      + n16] = a10[r];
        Z[(row0 + 16) * 36 + 16 + n16] = a11[r];
      }
    }
    __syncthreads();
    if (kq != 0) {
#pragma unroll
      for (int r = 0; r < 4; ++r) {
        int row0 = mh * 32 + q * 4 + r;
        atomicAdd(&Z[ row0       * 36      + n16], a00[r]);
        atomicAdd(&Z[ row0       * 36 + 16 + n16], a01[r]);
        atomicAdd(&Z[(row0 + 16) * 36      + n16], a10[r]);
        atomicAdd(&Z[(row0 + 16) * 36 + 16 + n16], a11[r]);
      }
    }
    __syncthreads();

    // ---- gates + cell update: one (batch, col) per thread ----
    float zi = Z[eb * 36      + ej] + bi;
    float zg = Z[eb * 36 +  8 + ej] + bg;
    float zf = Z[eb * 36 + 16 + ej] + bfg;
    float zo = Z[eb * 36 + 24 + ej] + bo;
    float ig = sigmoidf_(zi);
    float g  = fmaxf(zg, 0.0f);
    float ff = sigmoidf_(zf);
    float oo = sigmoidf_(zo);
    cst = ff * cst + ig * g;
    float hn = oo * fmaxf(cst, 0.0f);
    llvm_amdgcn_raw_buffer_store_i16((short)f2bf(hn), hsrd,
                                     t * (Bsz * Hn * 2) + hst_off, 0, 17);

    // ---- grid barrier: pure relaxed agent atomics (no wbl2/inv cache walks) ----
    // __syncthreads drains each wave's vmcnt(0); sc1 store acks come from the IF
    // coherence point, so data is globally visible before tid0 signals arrive.
    if (t < Tn - 1) {
      __syncthreads();
      if (tid == 0) {
        unsigned target = (unsigned)t + 1u;
        unsigned old = __hip_atomic_fetch_add(arrive, 1u, __ATOMIC_RELAXED, __HIP_MEMORY_SCOPE_AGENT);
        if (old == target * NBLK - 1u) {
          __hip_atomic_store(release, target, __ATOMIC_RELAXED, __HIP_MEMORY_SCOPE_AGENT);
        } else {
          while (__hip_atomic_load(release, __ATOMIC_RELAXED, __HIP_MEMORY_SCOPE_AGENT) < target) {
            __builtin_amdgcn_s_sleep(4);
          }
        }
      }
      asm volatile("" ::: "memory");
      __syncthreads();
    }
  }
}

// ---------------- dense epilogue: out[b,t,:] = hs_row @ Wd + bd ----------------
__global__ __launch_bounds__(256) void dense_kernel(
    const unsigned short* __restrict__ hs,    // [32768][1024] bf16, row = t*64+b
    const unsigned short* __restrict__ WdT,   // [128][1024] bf16
    const float* __restrict__ bd,             // [128]
    float* __restrict__ out)                  // [64][512][128] fp32
{
  const int tid = threadIdx.x;
  const int w = tid >> 6, l = tid & 63, q = l >> 4, n16 = l & 15;
  const int R0 = blockIdx.x * 64 + w * 16;
  f32x4 acc[8];
#pragma unroll
  for (int i = 0; i < 8; ++i) acc[i] = (f32x4){0, 0, 0, 0};
  const unsigned short* arow = hs + (size_t)(R0 + n16) * Hn + q * 8;
#pragma unroll 4
  for (int ks = 0; ks < 32; ++ks) {
    bf16x8 A = *(const bf16x8*)(arow + ks * 32);
#pragma unroll
    for (int nt = 0; nt < 8; ++nt) {
      bf16x8 Bf = *(const bf16x8*)(WdT + (size_t)(nt * 16 + n16) * Hn + ks * 32 + q * 8);
      acc[nt] = __builtin_amdgcn_mfma_f32_16x16x32_bf16(A, Bf, acc[nt], 0, 0, 0);
    }
  }
#pragma unroll
  for (int nt = 0; nt < 8; ++nt) {
    int col = nt * 16 + n16;
    float bdv = bd[col];
#pragma unroll
    for (int r = 0; r < 4; ++r) {
      int R = R0 + q * 4 + r;
      int b = R & 63, t = R >> 6;
      out[((size_t)b * Tn + t) * 128 + col] = acc[nt][r] + bdv;
    }
  }
}

// ---------------- launcher ----------------
extern "C" void kernel_launch(void* const* d_in, const int* in_sizes, int n_in,
                              void* d_out, int out_size, void* d_ws, size_t ws_size,
                              hipStream_t stream) {
  const float* X    = (const float*)d_in[0];   // [64][512][128]
  const float* Wk   = (const float*)d_in[1];   // [1152][4096]
  const float* bias = (const float*)d_in[2];   // [4096]
  const float* Wd   = (const float*)d_in[3];   // [1024][128]
  const float* bd   = (const float*)d_in[4];   // [128]
  float* out = (float*)d_out;

  // ws layout (bytes):
  char* ws = (char*)d_ws;
  unsigned short* Xb  = (unsigned short*)(ws);              //  8,388,608
  unsigned short* WkT = (unsigned short*)(ws + 8388608);    //  9,437,184
  unsigned short* WdT = (unsigned short*)(ws + 17825792);   //    262,144
  unsigned short* hs  = (unsigned short*)(ws + 18087936);   // 67,108,864
  unsigned*       syn = (unsigned*)      (ws + 85196800);   //        512

  hipMemsetAsync(syn, 0, 512, stream);
  cast_x_kernel<<<4096, 256, 0, stream>>>(X, Xb);
  transpose_cast_kernel<<<1152, 256, 0, stream>>>(Wk, WkT, 1152, 4096, 1152, 18);
  transpose_cast_kernel<<<32, 256, 0, stream>>>(Wd, WdT, 1024, 128, 1024, 16);
  // arrive = syn[0]; release = syn[64] -> 256 B apart (different 128 B lines,
  // so 127 pollers don't contend with the arrival atomics).
  lstm_kernel<<<NBLK, 512, 0, stream>>>(Xb, WkT, bias, hs, syn, syn + 64);
  dense_kernel<<<512, 256, 0, stream>>>(hs, WdT, bd, out);
}

// Round 3
// 3712.550 us; speedup vs baseline: 2.4206x; 2.0327x over previous
//
#include <hip/hip_runtime.h>
#include <math.h>

// Problem: B=64, T=512, I=128, H=1024, O=128; gates order i,j,f,o; relu activations.
#define Bsz 64
#define Tn  512
#define In  128
#define Hn  1024
#define KT  1152      // I + H
#define NBLK 128      // persistent blocks; each owns 8 hidden cols (x4 gates = 32 cols)

typedef __attribute__((ext_vector_type(8))) short bf16x8;   // 8 bf16 = 4 VGPRs (MFMA A/B frag)
typedef __attribute__((ext_vector_type(4))) short s16x4;
typedef __attribute__((ext_vector_type(4))) float f32x4;
typedef __attribute__((ext_vector_type(4))) int   i32x4;

// Raw buffer intrinsics. cpol 17 = SC0|SC1 on gfx950 -> performed at the IF/MALL
// coherence point (cross-XCD coherent), no L2 cache-walk fences needed.
__device__ void llvm_amdgcn_raw_buffer_store_i16(short vdata, i32x4 srsrc, int voffset, int soffset, int cpol) __asm("llvm.amdgcn.raw.buffer.store.i16");

__device__ __forceinline__ i32x4 make_srd(const void* p, int bytes) {
  i32x4 r;
  r.x = (int)(unsigned)(unsigned long long)p;
  r.y = (int)((unsigned long long)p >> 32);   // stride = 0
  r.z = bytes;                                // num_records (bytes when stride==0)
  r.w = 0x00020000;                           // raw dword access
  return r;
}

__device__ __forceinline__ unsigned short f2bf(float f) {
  union { float f; unsigned u; } x; x.f = f;
  unsigned r = x.u + 0x7FFFu + ((x.u >> 16) & 1u);   // RNE
  return (unsigned short)(r >> 16);
}
__device__ __forceinline__ float sigmoidf_(float x) { return 1.0f / (1.0f + __expf(-x)); }

// ---------------- prep: X (fp32) -> Xb (bf16), elementwise ----------------
__global__ __launch_bounds__(256) void cast_x_kernel(const float* __restrict__ in,
                                                     unsigned short* __restrict__ out) {
  int i = blockIdx.x * 256 + threadIdx.x;
  f32x4 v = ((const f32x4*)in)[i];
  s16x4 o;
  o.x = (short)f2bf(v.x); o.y = (short)f2bf(v.y);
  o.z = (short)f2bf(v.z); o.w = (short)f2bf(v.w);
  ((s16x4*)out)[i] = o;
}

// -------- prep: transpose+cast fp32 [R][C] -> bf16 [C][ldo] (64x64 LDS tiles) --------
__global__ __launch_bounds__(256) void transpose_cast_kernel(const float* __restrict__ in,
                                                             unsigned short* __restrict__ out,
                                                             int R, int C, int ldo, int tilesR) {
  __shared__ unsigned short tile[64][73];
  int br = blockIdx.x % tilesR, bc = blockIdx.x / tilesR;
  int r0 = br << 6, c0 = bc << 6;
  for (int e = threadIdx.x; e < 4096; e += 256) {
    int r = e >> 6, c = e & 63;
    tile[r][c] = f2bf(in[(size_t)(r0 + r) * C + (c0 + c)]);
  }
  __syncthreads();
  for (int e = threadIdx.x; e < 4096; e += 256) {
    int c = e >> 6, r = e & 63;
    out[(size_t)(c0 + c) * ldo + (r0 + r)] = tile[r][c];
  }
}

// ---------------- persistent LSTM recurrence ----------------
// Block blk owns hidden cols j in [blk*8, blk*8+8), gate cols {j, H+j, 2H+j, 3H+j}.
// 8 waves = (2 batch-halves mh) x (4 K-quarters kq); B-frags register-resident.
// Sync: per-block completion flags; each WAVE polls only its producer subset
// (line-aligned superset of the k-slice it loads) -> pipelined all-to-all.
// h stores write-through to MALL (sc0|sc1); h loads are PLAIN (virgin addresses,
// so L2-cached reads are coherent regardless of XCD placement, and the 16
// blocks/XCD share one L2 fetch of each h line instead of 16 MALL streams).
__global__ __launch_bounds__(512, 1) void lstm_kernel(
    const unsigned short* __restrict__ Xb,    // [64][512][128] bf16
    const unsigned short* __restrict__ WkT,   // [4096][1152]  bf16 (col-major-in-k)
    const float* __restrict__ bias,           // [4096]
    unsigned short* __restrict__ hs,          // [512][64][1024] bf16 (output history)
    unsigned* __restrict__ flags)             // [NBLK] steps-completed per block
{
  __shared__ float Z4[4][64][36];             // per-kq partials [kq][batch][32 cols], ld 36
  const int tid = threadIdx.x;
  const int blk = blockIdx.x;
  const int w   = tid >> 6;
  const int mh  = w & 1;                      // batch half (32 rows)
  const int kq  = w >> 1;                     // K quarter (288 of 1152)
  const int l   = tid & 63, q = l >> 4, n16 = l & 15;

  const i32x4 hsrd = make_srd(hs, Tn * Bsz * Hn * 2);

  // ---- load register-resident B fragments (once) ----
  bf16x8 Bf[2][9];
#pragma unroll
  for (int nt = 0; nt < 2; ++nt) {
    int cl   = nt * 16 + n16;                                  // local col 0..31
    int gcol = (cl >> 3) * Hn + blk * 8 + (cl & 7);            // gate*1024 + j
    const unsigned short* bp = WkT + (size_t)gcol * KT + kq * 288 + q * 8;
#pragma unroll
    for (int ks = 0; ks < 9; ++ks)
      Bf[nt][ks] = *(const bf16x8*)(bp + ks * 32);
  }

  // ---- epilogue constants: thread = (batch eb, col ej) ----
  const int eb = tid >> 3, ej = tid & 7;
  const float bi  = bias[           blk * 8 + ej];
  const float bg  = bias[    Hn   + blk * 8 + ej];
  const float bfg = bias[2 * Hn   + blk * 8 + ej] + 1.0f;      // TF forget bias
  const float bo  = bias[3 * Hn   + blk * 8 + ej];
  const int   hst_off = (eb * Hn + blk * 8 + ej) * 2;          // per-thread h store (byte, sans t)
  float cst = 0.0f;                                            // cell state, persistent in VGPR

  const int b0 = mh * 32 + n16;                                // A rows (two 16-batch tiles)
  const int b1 = b0 + 16;

  // ---- per-wave producer poll range (128B-line-aligned superset of k-slice) ----
  // wave kq loads h cols: kq0 [0,160) kq1 [160,448) kq2 [448,736) kq3 [736,1024)
  // line(64-col)-aligned -> blocks: [0,24) [16,56) [56,96) [88,128)
  const int pbase = (kq == 0) ? 0 : (kq == 1) ? 16 : (kq == 2) ? 56 : 88;
  const int pcnt  = (kq == 0) ? 24 : 40;
  const int pidx  = pbase + ((l < pcnt) ? l : 0);

  for (int t = 0; t < Tn; ++t) {
    f32x4 a00 = {0,0,0,0}, a01 = {0,0,0,0}, a10 = {0,0,0,0}, a11 = {0,0,0,0};

    if (t > 0) {
      // x-part A-frags don't depend on flags: prefetch before polling (kq0 only)
      bf16x8 X0[4], X1[4];
      if (kq == 0) {
#pragma unroll
        for (int ks = 0; ks < 4; ++ks) {
          X0[ks] = *(const bf16x8*)(Xb + ((size_t)b0 * Tn + t) * In + ks * 32 + q * 8);
          X1[ks] = *(const bf16x8*)(Xb + ((size_t)b1 * Tn + t) * In + ks * 32 + q * 8);
        }
      }
      // wave-local poll: wait until this wave's producers finished step t-1
      for (;;) {
        unsigned f = __hip_atomic_load(&flags[pidx], __ATOMIC_RELAXED, __HIP_MEMORY_SCOPE_AGENT);
        bool ok = (l >= pcnt) || (f >= (unsigned)t);
        if (__ballot(ok) == ~0ull) break;
      }
      const unsigned short* hrow = hs + (size_t)(t - 1) * (Bsz * Hn);
#pragma unroll
      for (int ks = 0; ks < 9; ++ks) {
        bf16x8 A0, A1;
        if (kq == 0 && ks < 4) {
          A0 = X0[ks]; A1 = X1[ks];
        } else {
          int kh = kq * 288 + ks * 32 - 128 + q * 8;           // h col
          A0 = *(const bf16x8*)(hrow + (size_t)b0 * Hn + kh);
          A1 = *(const bf16x8*)(hrow + (size_t)b1 * Hn + kh);
        }
        a00 = __builtin_amdgcn_mfma_f32_16x16x32_bf16(A0, Bf[0][ks], a00, 0, 0, 0);
        a01 = __builtin_amdgcn_mfma_f32_16x16x32_bf16(A0, Bf[1][ks], a01, 0, 0, 0);
        a10 = __builtin_amdgcn_mfma_f32_16x16x32_bf16(A1, Bf[0][ks], a10, 0, 0, 0);
        a11 = __builtin_amdgcn_mfma_f32_16x16x32_bf16(A1, Bf[1][ks], a11, 0, 0, 0);
      }
    } else if (kq == 0) {                                      // t==0: h==0, x-part only
#pragma unroll
      for (int ks = 0; ks < 4; ++ks) {
        const unsigned short* x0 = Xb + ((size_t)b0 * Tn) * In + ks * 32 + q * 8;
        const unsigned short* x1 = Xb + ((size_t)b1 * Tn) * In + ks * 32 + q * 8;
        bf16x8 A0 = *(const bf16x8*)x0, A1 = *(const bf16x8*)x1;
        a00 = __builtin_amdgcn_mfma_f32_16x16x32_bf16(A0, Bf[0][ks], a00, 0, 0, 0);
        a01 = __builtin_amdgcn_mfma_f32_16x16x32_bf16(A0, Bf[1][ks], a01, 0, 0, 0);
        a10 = __builtin_amdgcn_mfma_f32_16x16x32_bf16(A1, Bf[0][ks], a10, 0, 0, 0);
        a11 = __builtin_amdgcn_mfma_f32_16x16x32_bf16(A1, Bf[1][ks], a11, 0, 0, 0);
      }
    }

    // ---- write per-kq partials (no atomics) ----
#pragma unroll
    for (int r = 0; r < 4; ++r) {
      int row = mh * 32 + q * 4 + r;
      Z4[kq][row     ][     n16] = a00[r];
      Z4[kq][row     ][16 + n16] = a01[r];
      Z4[kq][row + 16][     n16] = a10[r];
      Z4[kq][row + 16][16 + n16] = a11[r];
    }
    __syncthreads();

    // ---- gates + cell update: one (batch, col) per thread; sum 4 kq partials ----
    float zi = bi, zg = bg, zf = bfg, zo = bo;
#pragma unroll
    for (int k2 = 0; k2 < 4; ++k2) {
      zi += Z4[k2][eb][     ej];
      zg += Z4[k2][eb][ 8 + ej];
      zf += Z4[k2][eb][16 + ej];
      zo += Z4[k2][eb][24 + ej];
    }
    float ig = sigmoidf_(zi);
    float g  = fmaxf(zg, 0.0f);
    float ff = sigmoidf_(zf);
    float oo = sigmoidf_(zo);
    cst = ff * cst + ig * g;
    float hn = oo * fmaxf(cst, 0.0f);
    llvm_amdgcn_raw_buffer_store_i16((short)f2bf(hn), hsrd,
                                     t * (Bsz * Hn * 2) + hst_off, 0, 17);

    // __syncthreads drains every wave's vmcnt(0): sc1 store acks come from the
    // coherence point, so h(t) is globally visible before the flag is set.
    __syncthreads();
    if (t < Tn - 1 && tid == 0) {
      __hip_atomic_store(&flags[blk], (unsigned)(t + 1), __ATOMIC_RELAXED, __HIP_MEMORY_SCOPE_AGENT);
    }
  }
}

// ---------------- dense epilogue: out[b,t,:] = hs_row @ Wd + bd ----------------
__global__ __launch_bounds__(256) void dense_kernel(
    const unsigned short* __restrict__ hs,    // [32768][1024] bf16, row = t*64+b
    const unsigned short* __restrict__ WdT,   // [128][1024] bf16
    const float* __restrict__ bd,             // [128]
    float* __restrict__ out)                  // [64][512][128] fp32
{
  const int tid = threadIdx.x;
  const int w = tid >> 6, l = tid & 63, q = l >> 4, n16 = l & 15;
  const int R0 = blockIdx.x * 64 + w * 16;
  f32x4 acc[8];
#pragma unroll
  for (int i = 0; i < 8; ++i) acc[i] = (f32x4){0, 0, 0, 0};
  const unsigned short* arow = hs + (size_t)(R0 + n16) * Hn + q * 8;
#pragma unroll 4
  for (int ks = 0; ks < 32; ++ks) {
    bf16x8 A = *(const bf16x8*)(arow + ks * 32);
#pragma unroll
    for (int nt = 0; nt < 8; ++nt) {
      bf16x8 Bf = *(const bf16x8*)(WdT + (size_t)(nt * 16 + n16) * Hn + ks * 32 + q * 8);
      acc[nt] = __builtin_amdgcn_mfma_f32_16x16x32_bf16(A, Bf, acc[nt], 0, 0, 0);
    }
  }
#pragma unroll
  for (int nt = 0; nt < 8; ++nt) {
    int col = nt * 16 + n16;
    float bdv = bd[col];
#pragma unroll
    for (int r = 0; r < 4; ++r) {
      int R = R0 + q * 4 + r;
      int b = R & 63, t = R >> 6;
      out[((size_t)b * Tn + t) * 128 + col] = acc[nt][r] + bdv;
    }
  }
}

// ---------------- launcher ----------------
extern "C" void kernel_launch(void* const* d_in, const int* in_sizes, int n_in,
                              void* d_out, int out_size, void* d_ws, size_t ws_size,
                              hipStream_t stream) {
  const float* X    = (const float*)d_in[0];   // [64][512][128]
  const float* Wk   = (const float*)d_in[1];   // [1152][4096]
  const float* bias = (const float*)d_in[2];   // [4096]
  const float* Wd   = (const float*)d_in[3];   // [1024][128]
  const float* bd   = (const float*)d_in[4];   // [128]
  float* out = (float*)d_out;

  // ws layout (bytes):
  char* ws = (char*)d_ws;
  unsigned short* Xb  = (unsigned short*)(ws);              //  8,388,608
  unsigned short* WkT = (unsigned short*)(ws + 8388608);    //  9,437,184
  unsigned short* WdT = (unsigned short*)(ws + 17825792);   //    262,144
  unsigned short* hs  = (unsigned short*)(ws + 18087936);   // 67,108,864
  unsigned*       syn = (unsigned*)      (ws + 85196800);   //      1,024 (flags[128])

  hipMemsetAsync(syn, 0, 1024, stream);
  cast_x_kernel<<<4096, 256, 0, stream>>>(X, Xb);
  transpose_cast_kernel<<<1152, 256, 0, stream>>>(Wk, WkT, 1152, 4096, 1152, 18);
  transpose_cast_kernel<<<32, 256, 0, stream>>>(Wd, WdT, 1024, 128, 1024, 16);
  lstm_kernel<<<NBLK, 512, 0, stream>>>(Xb, WkT, bias, hs, syn);
  dense_kernel<<<512, 256, 0, stream>>>(hs, WdT, bd, out);
}

// Round 5
// 3025.971 us; speedup vs baseline: 2.9699x; 1.2269x over previous
//
#include <hip/hip_runtime.h>
#include <math.h>

// Problem: B=64, T=512, I=128, H=1024, O=128; gates order i,j,f,o; relu activations.
#define Bsz 64
#define Tn  512
#define In  128
#define Hn  1024
#define KT  1152      // I + H
#define NBLK 128      // persistent blocks; each owns 8 hidden cols (x4 gates = 32 cols)

// syn (u32 word indices), each hot word on its own 128B line:
//   group arrive counters: S[32*g],        g=0..7  (monotone, 16 arrivals/step)
//   group step flags:      S[512 + 32*g],  g=0..7  (value v => h(0..v-1) visible)
#define GARR0 0
#define GFLG0 512

typedef __attribute__((ext_vector_type(8))) short bf16x8;   // 8 bf16 = 4 VGPRs (MFMA A/B frag)
typedef __attribute__((ext_vector_type(4))) short s16x4;
typedef __attribute__((ext_vector_type(4))) float f32x4;
typedef __attribute__((ext_vector_type(4))) int   i32x4;

// Raw buffer store, cpol 17 = SC0|SC1 on gfx950 -> write-through to the IF/MALL
// coherence point (cross-XCD visible without any cache-walk fences). [R2/R3-proven]
__device__ void llvm_amdgcn_raw_buffer_store_i16(short vdata, i32x4 srsrc, int voffset, int soffset, int cpol) __asm("llvm.amdgcn.raw.buffer.store.i16");

__device__ __forceinline__ i32x4 make_srd(const void* p, int bytes) {
  i32x4 r;
  r.x = (int)(unsigned)(unsigned long long)p;
  r.y = (int)((unsigned long long)p >> 32);   // stride = 0
  r.z = bytes;                                // num_records (bytes when stride==0)
  r.w = 0x00020000;                           // raw dword access
  return r;
}

__device__ __forceinline__ unsigned short f2bf(float f) {
  union { float f; unsigned u; } x; x.f = f;
  unsigned r = x.u + 0x7FFFu + ((x.u >> 16) & 1u);   // RNE
  return (unsigned short)(r >> 16);
}
__device__ __forceinline__ float sigmoidf_(float x) { return 1.0f / (1.0f + __expf(-x)); }

// ---------------- prep: X (fp32) -> Xb (bf16), elementwise ----------------
__global__ __launch_bounds__(256) void cast_x_kernel(const float* __restrict__ in,
                                                     unsigned short* __restrict__ out) {
  int i = blockIdx.x * 256 + threadIdx.x;
  f32x4 v = ((const f32x4*)in)[i];
  s16x4 o;
  o.x = (short)f2bf(v.x); o.y = (short)f2bf(v.y);
  o.z = (short)f2bf(v.z); o.w = (short)f2bf(v.w);
  ((s16x4*)out)[i] = o;
}

// -------- prep: transpose+cast fp32 [R][C] -> bf16 [C][ldo] (64x64 LDS tiles) --------
__global__ __launch_bounds__(256) void transpose_cast_kernel(const float* __restrict__ in,
                                                             unsigned short* __restrict__ out,
                                                             int R, int C, int ldo, int tilesR) {
  __shared__ unsigned short tile[64][73];
  int br = blockIdx.x % tilesR, bc = blockIdx.x / tilesR;
  int r0 = br << 6, c0 = bc << 6;
  for (int e = threadIdx.x; e < 4096; e += 256) {
    int r = e >> 6, c = e & 63;
    tile[r][c] = f2bf(in[(size_t)(r0 + r) * C + (c0 + c)]);
  }
  __syncthreads();
  for (int e = threadIdx.x; e < 4096; e += 256) {
    int c = e >> 6, r = e & 63;
    out[(size_t)(c0 + c) * ldo + (r0 + r)] = tile[r][c];
  }
}

// ---------------- persistent LSTM recurrence ----------------
// Block blk owns hidden cols j in [blk*8, blk*8+8), gate cols {j, H+j, 2H+j, 3H+j}.
// 8 waves = (2 batch-halves mh) x (4 K-quarters kq); B-frags register-resident.
// Sync (hierarchical, static, proven primitives only):
//   arrive: tid0 agent fetch_add on group counter (grp = blk>>4, 16 blocks/group);
//           16th arriver posts group flag = t+1 (agent store).
//   wait:   each WAVE polls only the <=3 group flags covering its h k-slice
//           (lanes 0..7, ballot) with s_sleep backoff -> pipelined, low MALL traffic.
// h hand-off: sc1 write-through stores (MALL-acked at the __syncthreads vmcnt drain
// BEFORE the arrive); consumer loads PLAIN -> per-XCD L2-shared, virgin t-lines.
__global__ __launch_bounds__(512, 1) void lstm_kernel(
    const unsigned short* __restrict__ Xb,    // [64][512][128] bf16
    const unsigned short* __restrict__ WkT,   // [4096][1152]  bf16 (col-major-in-k)
    const float* __restrict__ bias,           // [4096]
    unsigned short* __restrict__ hs,          // [512][64][1024] bf16 (output history)
    unsigned* __restrict__ S)                 // sync area (4 KB, zeroed)
{
  __shared__ float Z4[4][64][36];             // per-kq partials [kq][batch][32 cols], ld 36
  const int tid = threadIdx.x;
  const int blk = blockIdx.x;
  const int grp = blk >> 4;                   // 8 static groups of 16 blocks
  const int w   = tid >> 6;
  const int mh  = w & 1;                      // batch half (32 rows)
  const int kq  = w >> 1;                     // K quarter (288 of 1152)
  const int l   = tid & 63, q = l >> 4, n16 = l & 15;

  const i32x4 hsrd = make_srd(hs, Tn * Bsz * Hn * 2);

  // ---- load register-resident B fragments (once) ----
  bf16x8 Bf[2][9];
#pragma unroll
  for (int nt = 0; nt < 2; ++nt) {
    int cl   = nt * 16 + n16;                                  // local col 0..31
    int gcol = (cl >> 3) * Hn + blk * 8 + (cl & 7);            // gate*1024 + j
    const unsigned short* bp = WkT + (size_t)gcol * KT + kq * 288 + q * 8;
#pragma unroll
    for (int ks = 0; ks < 9; ++ks)
      Bf[nt][ks] = *(const bf16x8*)(bp + ks * 32);
  }

  // ---- epilogue constants: thread = (batch eb, col ej) ----
  const int eb = tid >> 3, ej = tid & 7;
  const float bi  = bias[           blk * 8 + ej];
  const float bg  = bias[    Hn   + blk * 8 + ej];
  const float bfg = bias[2 * Hn   + blk * 8 + ej] + 1.0f;      // TF forget bias
  const float bo  = bias[3 * Hn   + blk * 8 + ej];
  const int   hst_off = (eb * Hn + blk * 8 + ej) * 2;          // per-thread h store (byte, sans t)
  float cst = 0.0f;                                            // cell state, persistent in VGPR

  const int b0 = mh * 32 + n16;                                // A rows (two 16-batch tiles)
  const int b1 = b0 + 16;

  // ---- per-wave producer-group mask (group g covers h cols [128g,128g+128)) ----
  // wave kq h-cols: kq0 [0,160) kq1 [160,448) kq2 [448,736) kq3 [736,1024)
  const unsigned needm = (kq == 0) ? 0x03u : (kq == 1) ? 0x0Eu : (kq == 2) ? 0x38u : 0xE0u;
  const bool mine = (l < 8) && ((needm >> l) & 1u);

  for (int t = 0; t < Tn; ++t) {
    f32x4 a00 = {0,0,0,0}, a01 = {0,0,0,0}, a10 = {0,0,0,0}, a11 = {0,0,0,0};

    if (t > 0) {
      // x-part A-frags don't depend on flags: prefetch before polling (kq0 only)
      bf16x8 X0[4], X1[4];
      if (kq == 0) {
#pragma unroll
        for (int ks = 0; ks < 4; ++ks) {
          X0[ks] = *(const bf16x8*)(Xb + ((size_t)b0 * Tn + t) * In + ks * 32 + q * 8);
          X1[ks] = *(const bf16x8*)(Xb + ((size_t)b1 * Tn + t) * In + ks * 32 + q * 8);
        }
      }
      // wave-local wait: this wave's producer GROUPS must have finished step t-1
      for (;;) {
        unsigned f = mine ? __hip_atomic_load(&S[GFLG0 + 32 * l], __ATOMIC_RELAXED,
                                              __HIP_MEMORY_SCOPE_AGENT)
                          : 0xFFFFFFFFu;
        if (__ballot(f >= (unsigned)t) == ~0ull) break;
        __builtin_amdgcn_s_sleep(1);          // ~64cy backoff: pace the MALL poll storm
      }
      const unsigned short* hrow = hs + (size_t)(t - 1) * (Bsz * Hn);
#pragma unroll
      for (int ks = 0; ks < 9; ++ks) {
        bf16x8 A0, A1;
        if (kq == 0 && ks < 4) {
          A0 = X0[ks]; A1 = X1[ks];
        } else {
          int kh = kq * 288 + ks * 32 - 128 + q * 8;           // h col
          A0 = *(const bf16x8*)(hrow + (size_t)b0 * Hn + kh);
          A1 = *(const bf16x8*)(hrow + (size_t)b1 * Hn + kh);
        }
        a00 = __builtin_amdgcn_mfma_f32_16x16x32_bf16(A0, Bf[0][ks], a00, 0, 0, 0);
        a01 = __builtin_amdgcn_mfma_f32_16x16x32_bf16(A0, Bf[1][ks], a01, 0, 0, 0);
        a10 = __builtin_amdgcn_mfma_f32_16x16x32_bf16(A1, Bf[0][ks], a10, 0, 0, 0);
        a11 = __builtin_amdgcn_mfma_f32_16x16x32_bf16(A1, Bf[1][ks], a11, 0, 0, 0);
      }
    } else if (kq == 0) {                                      // t==0: h==0, x-part only
#pragma unroll
      for (int ks = 0; ks < 4; ++ks) {
        bf16x8 A0 = *(const bf16x8*)(Xb + ((size_t)b0 * Tn) * In + ks * 32 + q * 8);
        bf16x8 A1 = *(const bf16x8*)(Xb + ((size_t)b1 * Tn) * In + ks * 32 + q * 8);
        a00 = __builtin_amdgcn_mfma_f32_16x16x32_bf16(A0, Bf[0][ks], a00, 0, 0, 0);
        a01 = __builtin_amdgcn_mfma_f32_16x16x32_bf16(A0, Bf[1][ks], a01, 0, 0, 0);
        a10 = __builtin_amdgcn_mfma_f32_16x16x32_bf16(A1, Bf[0][ks], a10, 0, 0, 0);
        a11 = __builtin_amdgcn_mfma_f32_16x16x32_bf16(A1, Bf[1][ks], a11, 0, 0, 0);
      }
    }

    // ---- write per-kq partials (no atomics) ----
#pragma unroll
    for (int r = 0; r < 4; ++r) {
      int row = mh * 32 + q * 4 + r;
      Z4[kq][row     ][     n16] = a00[r];
      Z4[kq][row     ][16 + n16] = a01[r];
      Z4[kq][row + 16][     n16] = a10[r];
      Z4[kq][row + 16][16 + n16] = a11[r];
    }
    __syncthreads();

    // ---- gates + cell update: one (batch, col) per thread; sum 4 kq partials ----
    float zi = bi, zg = bg, zf = bfg, zo = bo;
#pragma unroll
    for (int k2 = 0; k2 < 4; ++k2) {
      zi += Z4[k2][eb][     ej];
      zg += Z4[k2][eb][ 8 + ej];
      zf += Z4[k2][eb][16 + ej];
      zo += Z4[k2][eb][24 + ej];
    }
    float ig = sigmoidf_(zi);
    float g  = fmaxf(zg, 0.0f);
    float ff = sigmoidf_(zf);
    float oo = sigmoidf_(zo);
    cst = ff * cst + ig * g;
    float hn = oo * fmaxf(cst, 0.0f);
    llvm_amdgcn_raw_buffer_store_i16((short)f2bf(hn), hsrd,
                                     t * (Bsz * Hn * 2) + hst_off, 0, 17);

    // __syncthreads drains every wave's vmcnt(0): sc1 store acks come from the
    // coherence point, so h(t) is globally visible before the arrive below.
    __syncthreads();
    if (t < Tn - 1 && tid == 0) {
      const unsigned tgt = (unsigned)t + 1u;
      unsigned old = __hip_atomic_fetch_add(&S[GARR0 + 32 * grp], 1u,
                                            __ATOMIC_RELAXED, __HIP_MEMORY_SCOPE_AGENT);
      if (old == 16u * tgt - 1u)              // 16th arriver of this group at step t
        __hip_atomic_store(&S[GFLG0 + 32 * grp], tgt,
                           __ATOMIC_RELAXED, __HIP_MEMORY_SCOPE_AGENT);
    }
  }
}

// ---------------- dense epilogue: out[b,t,:] = hs_row @ Wd + bd ----------------
__global__ __launch_bounds__(256) void dense_kernel(
    const unsigned short* __restrict__ hs,    // [32768][1024] bf16, row = t*64+b
    const unsigned short* __restrict__ WdT,   // [128][1024] bf16
    const float* __restrict__ bd,             // [128]
    float* __restrict__ out)                  // [64][512][128] fp32
{
  const int tid = threadIdx.x;
  const int w = tid >> 6, l = tid & 63, q = l >> 4, n16 = l & 15;
  const int R0 = blockIdx.x * 64 + w * 16;
  f32x4 acc[8];
#pragma unroll
  for (int i = 0; i < 8; ++i) acc[i] = (f32x4){0, 0, 0, 0};
  const unsigned short* arow = hs + (size_t)(R0 + n16) * Hn + q * 8;
#pragma unroll 4
  for (int ks = 0; ks < 32; ++ks) {
    bf16x8 A = *(const bf16x8*)(arow + ks * 32);
#pragma unroll
    for (int nt = 0; nt < 8; ++nt) {
      bf16x8 Bf = *(const bf16x8*)(WdT + (size_t)(nt * 16 + n16) * Hn + ks * 32 + q * 8);
      acc[nt] = __builtin_amdgcn_mfma_f32_16x16x32_bf16(A, Bf, acc[nt], 0, 0, 0);
    }
  }
#pragma unroll
  for (int nt = 0; nt < 8; ++nt) {
    int col = nt * 16 + n16;
    float bdv = bd[col];
#pragma unroll
    for (int r = 0; r < 4; ++r) {
      int R = R0 + q * 4 + r;
      int b = R & 63, t = R >> 6;
      out[((size_t)b * Tn + t) * 128 + col] = acc[nt][r] + bdv;
    }
  }
}

// ---------------- launcher ----------------
extern "C" void kernel_launch(void* const* d_in, const int* in_sizes, int n_in,
                              void* d_out, int out_size, void* d_ws, size_t ws_size,
                              hipStream_t stream) {
  const float* X    = (const float*)d_in[0];   // [64][512][128]
  const float* Wk   = (const float*)d_in[1];   // [1152][4096]
  const float* bias = (const float*)d_in[2];   // [4096]
  const float* Wd   = (const float*)d_in[3];   // [1024][128]
  const float* bd   = (const float*)d_in[4];   // [128]
  float* out = (float*)d_out;

  // ws layout (bytes):
  char* ws = (char*)d_ws;
  unsigned short* Xb  = (unsigned short*)(ws);              //  8,388,608
  unsigned short* WkT = (unsigned short*)(ws + 8388608);    //  9,437,184
  unsigned short* WdT = (unsigned short*)(ws + 17825792);   //    262,144
  unsigned short* hs  = (unsigned short*)(ws + 18087936);   // 67,108,864
  unsigned*       syn = (unsigned*)      (ws + 85196800);   //      4,096 (sync area)

  hipMemsetAsync(syn, 0, 4096, stream);
  cast_x_kernel<<<4096, 256, 0, stream>>>(X, Xb);
  transpose_cast_kernel<<<1152, 256, 0, stream>>>(Wk, WkT, 1152, 4096, 1152, 18);
  transpose_cast_kernel<<<32, 256, 0, stream>>>(Wd, WdT, 1024, 128, 1024, 16);
  lstm_kernel<<<NBLK, 512, 0, stream>>>(Xb, WkT, bias, hs, syn);
  dense_kernel<<<512, 256, 0, stream>>>(hs, WdT, bd, out);
}